// Round 1
// baseline (1225.214 us; speedup 1.0000x reference)
//
#include <hip/hip_runtime.h>

#define NN 50000
#define NE 800000
#define DIM 64
#define TL 4
#define ET 3
#define MH 6

static __global__ void k_hist(const int* __restrict__ dst, int* __restrict__ counts) {
    int e = blockIdx.x * blockDim.x + threadIdx.x;
    if (e < NE) atomicAdd(&counts[dst[e]], 1);
}

static __global__ void k_scan(const int* __restrict__ counts,
                              int* __restrict__ row_start, int* __restrict__ cursor) {
    __shared__ int partial[1024];
    const int tid = threadIdx.x;
    const int CH = (NN + 1023) / 1024;  // 49
    int base = tid * CH;
    int s = 0;
    for (int i = 0; i < CH; ++i) { int idx = base + i; if (idx < NN) s += counts[idx]; }
    partial[tid] = s;
    __syncthreads();
    for (int off = 1; off < 1024; off <<= 1) {
        int v = (tid >= off) ? partial[tid - off] : 0;
        __syncthreads();
        partial[tid] += v;
        __syncthreads();
    }
    int run = (tid == 0) ? 0 : partial[tid - 1];
    for (int i = 0; i < CH; ++i) {
        int idx = base + i;
        if (idx < NN) { row_start[idx] = run; cursor[idx] = run; run += counts[idx]; }
    }
    if (tid == 1023) row_start[NN] = run;  // = total edges
}

static __global__ void k_scatter(const int* __restrict__ src, const int* __restrict__ dst,
                                 const int* __restrict__ hop, const int* __restrict__ typ,
                                 int* __restrict__ cursor,
                                 int* __restrict__ src_s, int* __restrict__ hop_s,
                                 int* __restrict__ typ_s) {
    int e = blockIdx.x * blockDim.x + threadIdx.x;
    if (e < NE) {
        int slot = atomicAdd(&cursor[dst[e]], 1);
        src_s[slot] = src[e];
        hop_s[slot] = hop[e];
        typ_s[slot] = typ[e];
    }
}

// One wave per node, lane = feature dim. Atomic-free aggregation via CSR.
template <int T>
static __global__ void k_agg(const int* __restrict__ row_start,
                             const int* __restrict__ src_s, const int* __restrict__ hop_s,
                             const int* __restrict__ typ_s,
                             const float* __restrict__ xt,
                             const float* __restrict__ d2, const float* __restrict__ d3,
                             const float* __restrict__ d4,
                             const float* __restrict__ nu_kt,
                             float* __restrict__ a0, float* __restrict__ a1,
                             float* __restrict__ a2, float* __restrict__ aH) {
    int g = blockIdx.x * blockDim.x + threadIdx.x;
    int node = g >> 6, lane = g & 63;
    if (node >= NN) return;
    int beg = row_start[node], end = row_start[node + 1];
    float s0 = 0.f, s1 = 0.f, s2 = 0.f, sH = 0.f;
    float nk2 = 0.f, nk3 = 0.f, nk4 = 0.f;
    if (T >= 1) nk2 = nu_kt[T * MH + 2];
    if (T >= 2) nk3 = nu_kt[T * MH + 3];
    if (T >= 3) nk4 = nu_kt[T * MH + 4];
    for (int e = beg; e < end; ++e) {
        int s = src_s[e];        // wave-uniform (broadcast load)
        int ty = typ_s[e];
        float xv = xt[s * DIM + lane];   // coalesced 256B gather
        s0 += (ty == 0) ? xv : 0.f;
        s1 += (ty == 1) ? xv : 0.f;
        s2 += (ty == 2) ? xv : 0.f;
        if (T >= 1) {
            int hp = hop_s[e];
            if (hp >= 2 && hp <= T + 1) {   // wave-uniform branch
                const float* hd = (hp == 2) ? d2 : (hp == 3) ? d3 : d4;
                float sc = (hp == 2) ? nk2 : (hp == 3) ? nk3 : nk4;
                sH = fmaf(sc, hd[s * DIM + lane], sH);
            }
        }
    }
    a0[g] = s0; a1[g] = s1; a2[g] = s2;
    if (T >= 1) aH[g] = sH;
}

// One wave per node, lane = output col. out = xin + relu(sum_b agg_b @ W_b + bias)
template <int T>
static __global__ void k_mm(const float* __restrict__ a0, const float* __restrict__ a1,
                            const float* __restrict__ a2, const float* __restrict__ aH,
                            const float* __restrict__ W_edge, const float* __restrict__ b_edge,
                            const float* __restrict__ nu_edge,
                            const float* __restrict__ W_t, const float* __restrict__ b_t,
                            const float* __restrict__ nu_kt,
                            const float* __restrict__ xin, float* __restrict__ xout) {
    int g = blockIdx.x * blockDim.x + threadIdx.x;
    int node = g >> 6, c = g & 63;
    if (node >= NN) return;
    float acc = 0.f;
#pragma unroll
    for (int e = 0; e < ET; ++e) {
        const float* A = (e == 0 ? a0 : e == 1 ? a1 : a2) + node * DIM;
        const float* W = W_edge + (size_t)(e * TL + T) * DIM * DIM + c;
        float p = 0.f;
#pragma unroll
        for (int d = 0; d < DIM; ++d) p = fmaf(A[d], W[d * DIM], p);
        float nu = nu_edge[e * TL + T];
        acc = fmaf(nu, p, acc);
        acc = fmaf(nu, b_edge[(e * TL + T) * DIM + c], acc);
    }
    if (T >= 1) {
        const float* A = aH + node * DIM;
        const float* W = W_t + (size_t)T * DIM * DIM + c;
        float p = 0.f;
#pragma unroll
        for (int d = 0; d < DIM; ++d) p = fmaf(A[d], W[d * DIM], p);
        acc += p;  // nu_kt already folded in at gather time
        float ns = 0.f;
#pragma unroll
        for (int k = 2; k <= T + 1; ++k) ns += nu_kt[T * MH + k];
        acc = fmaf(ns, b_t[T * DIM + c], acc);
    }
    float r = acc > 0.f ? acc : 0.f;
    xout[g] = xin[g] + r;
}

extern "C" void kernel_launch(void* const* d_in, const int* in_sizes, int n_in,
                              void* d_out, int out_size, void* d_ws, size_t ws_size,
                              hipStream_t stream) {
    const float* x       = (const float*)d_in[0];
    const float* W_edge  = (const float*)d_in[1];
    const float* b_edge  = (const float*)d_in[2];
    const float* nu_edge = (const float*)d_in[3];
    const float* W_t     = (const float*)d_in[4];
    const float* b_t     = (const float*)d_in[5];
    const float* nu_kt   = (const float*)d_in[6];
    const int* esrc = (const int*)d_in[7];
    const int* edst = (const int*)d_in[8];
    const int* ehop = (const int*)d_in[9];
    const int* etyp = (const int*)d_in[10];
    float* out = (float*)d_out;

    char* ws = (char*)d_ws;
    size_t off = 0;
    auto alloc = [&](size_t bytes) {
        void* p = ws + off;
        off = (off + bytes + 255) & ~(size_t)255;
        return p;
    };
    int* counts    = (int*)alloc(NN * 4);
    int* row_start = (int*)alloc((NN + 1) * 4);
    int* cursor    = (int*)alloc(NN * 4);
    int* src_s     = (int*)alloc(NE * 4);
    int* hop_s     = (int*)alloc(NE * 4);
    int* typ_s     = (int*)alloc(NE * 4);
    float* h1 = (float*)alloc((size_t)NN * DIM * 4);
    float* h2 = (float*)alloc((size_t)NN * DIM * 4);
    float* h3 = (float*)alloc((size_t)NN * DIM * 4);
    float* a0 = (float*)alloc((size_t)NN * DIM * 4);
    float* a1 = (float*)alloc((size_t)NN * DIM * 4);
    float* a2 = (float*)alloc((size_t)NN * DIM * 4);
    float* aH = (float*)alloc((size_t)NN * DIM * 4);
    (void)ws_size; (void)in_sizes; (void)n_in; (void)out_size;

    // ---- CSR build (once per call; graph is static across layers) ----
    hipMemsetAsync(counts, 0, NN * 4, stream);
    k_hist<<<(NE + 255) / 256, 256, 0, stream>>>(edst, counts);
    k_scan<<<1, 1024, 0, stream>>>(counts, row_start, cursor);
    k_scatter<<<(NE + 255) / 256, 256, 0, stream>>>(esrc, edst, ehop, etyp, cursor,
                                                    src_s, hop_s, typ_s);

    const int gb = (NN * DIM + 255) / 256;  // one wave per node
    // t = 0: hist = {x}
    k_agg<0><<<gb, 256, 0, stream>>>(row_start, src_s, hop_s, typ_s, x, x, x, x, nu_kt,
                                     a0, a1, a2, aH);
    k_mm<0><<<gb, 256, 0, stream>>>(a0, a1, a2, aH, W_edge, b_edge, nu_edge, W_t, b_t,
                                    nu_kt, x, h1);
    // t = 1: xs = {x, h1}; hop2 -> x
    k_agg<1><<<gb, 256, 0, stream>>>(row_start, src_s, hop_s, typ_s, h1, x, x, x, nu_kt,
                                     a0, a1, a2, aH);
    k_mm<1><<<gb, 256, 0, stream>>>(a0, a1, a2, aH, W_edge, b_edge, nu_edge, W_t, b_t,
                                    nu_kt, h1, h2);
    // t = 2: hop2 -> h1, hop3 -> x
    k_agg<2><<<gb, 256, 0, stream>>>(row_start, src_s, hop_s, typ_s, h2, h1, x, x, nu_kt,
                                     a0, a1, a2, aH);
    k_mm<2><<<gb, 256, 0, stream>>>(a0, a1, a2, aH, W_edge, b_edge, nu_edge, W_t, b_t,
                                    nu_kt, h2, h3);
    // t = 3: hop2 -> h2, hop3 -> h1, hop4 -> x
    k_agg<3><<<gb, 256, 0, stream>>>(row_start, src_s, hop_s, typ_s, h3, h2, h1, x, nu_kt,
                                     a0, a1, a2, aH);
    k_mm<3><<<gb, 256, 0, stream>>>(a0, a1, a2, aH, W_edge, b_edge, nu_edge, W_t, b_t,
                                    nu_kt, h3, out);
}

// Round 2
// 763.220 us; speedup vs baseline: 1.6053x; 1.6053x over previous
//
#include <hip/hip_runtime.h>

#define NN 50000
#define NE 800000
#define DIM 64
#define TL 4
#define ET 3
#define MH 6
#define NBKT 6
#define NB (NN * NBKT)
#define SCAN_BLK ((NB + 1023) / 1024)   // 293

// ---------------- CSR build: 6 buckets per node (T0,T1,T2,H2,H3,H4) ----------------

static __global__ void k_hist6(const int* __restrict__ dst, const int* __restrict__ typ,
                               const int* __restrict__ hop, int* __restrict__ counts) {
    int e = blockIdx.x * blockDim.x + threadIdx.x;
    if (e >= NE) return;
    int d = dst[e];
    atomicAdd(&counts[d * NBKT + typ[e]], 1);
    int h = hop[e];
    if (h >= 2 && h <= 4) atomicAdd(&counts[d * NBKT + h + 1], 1);  // buckets 3,4,5
}

static __global__ void k_scanA(const int* __restrict__ counts, int* __restrict__ rs,
                               int* __restrict__ bsum) {
    __shared__ int sm[1024];
    int idx = blockIdx.x * 1024 + threadIdx.x;
    int v = (idx < NB) ? counts[idx] : 0;
    sm[threadIdx.x] = v;
    __syncthreads();
    for (int off = 1; off < 1024; off <<= 1) {
        int t = (threadIdx.x >= off) ? sm[threadIdx.x - off] : 0;
        __syncthreads();
        sm[threadIdx.x] += t;
        __syncthreads();
    }
    if (idx < NB) rs[idx] = sm[threadIdx.x] - v;   // exclusive within block
    if (threadIdx.x == 1023) bsum[blockIdx.x] = sm[1023];
}

static __global__ void k_scanB(const int* __restrict__ bsum, int* __restrict__ bexcl,
                               int* __restrict__ rs) {
    __shared__ int sm[512];
    int tid = threadIdx.x;
    int v = (tid < SCAN_BLK) ? bsum[tid] : 0;
    sm[tid] = v;
    __syncthreads();
    for (int off = 1; off < 512; off <<= 1) {
        int t = (tid >= off) ? sm[tid - off] : 0;
        __syncthreads();
        sm[tid] += t;
        __syncthreads();
    }
    if (tid < SCAN_BLK) bexcl[tid] = sm[tid] - v;
    if (tid == 511) rs[NB] = sm[511];              // grand total
}

static __global__ void k_scanC(int* __restrict__ rs, int* __restrict__ cursor,
                               const int* __restrict__ bexcl) {
    int idx = blockIdx.x * 1024 + threadIdx.x;
    if (idx >= NB) return;
    int r = rs[idx] + bexcl[blockIdx.x];
    rs[idx] = r;
    cursor[idx] = r;
}

static __global__ void k_scatter6(const int* __restrict__ src, const int* __restrict__ dst,
                                  const int* __restrict__ typ, const int* __restrict__ hop,
                                  int* __restrict__ cursor, int* __restrict__ src_s) {
    int e = blockIdx.x * blockDim.x + threadIdx.x;
    if (e >= NE) return;
    int d = dst[e], s = src[e];
    int slot = atomicAdd(&cursor[d * NBKT + typ[e]], 1);
    src_s[slot] = s;
    int h = hop[e];
    if (h >= 2 && h <= 4) {
        slot = atomicAdd(&cursor[d * NBKT + h + 1], 1);
        src_s[slot] = s;
    }
}

// ---------------- Aggregation: one wave per node, srcs preloaded into lanes ----------------

__device__ __forceinline__ void sum_bucket(const float* __restrict__ p, int lane, int sv,
                                           int lo, int hi, float scale, float& acc,
                                           bool use_scale) {
    int i = lo;
    for (; i + 2 <= hi; i += 2) {
        int sa = __builtin_amdgcn_readlane(sv, i);
        int sb = __builtin_amdgcn_readlane(sv, i + 1);
        float va = p[(size_t)sa * DIM + lane];
        float vb = p[(size_t)sb * DIM + lane];
        if (use_scale) { acc = fmaf(scale, va, acc); acc = fmaf(scale, vb, acc); }
        else           { acc += va; acc += vb; }
    }
    if (i < hi) {
        int sa = __builtin_amdgcn_readlane(sv, i);
        float va = p[(size_t)sa * DIM + lane];
        acc = use_scale ? fmaf(scale, va, acc) : acc + va;
    }
}

__device__ __forceinline__ void sum_bucket_g(const float* __restrict__ p, int lane,
                                             const int* __restrict__ src_s, int lo, int hi,
                                             float scale, float& acc, bool use_scale) {
    for (int e = lo; e < hi; ++e) {
        int s = src_s[e];
        float v = p[(size_t)s * DIM + lane];
        acc = use_scale ? fmaf(scale, v, acc) : acc + v;
    }
}

template <int T>
static __global__ __launch_bounds__(256) void k_agg(
        const int* __restrict__ rs, const int* __restrict__ src_s,
        const float* __restrict__ xt, const float* __restrict__ d2,
        const float* __restrict__ d3, const float* __restrict__ d4,
        const float* __restrict__ nu_edge, const float* __restrict__ nu_kt,
        float* __restrict__ a0, float* __restrict__ a1,
        float* __restrict__ a2, float* __restrict__ aH) {
    int g = blockIdx.x * blockDim.x + threadIdx.x;
    int node = g >> 6;
    if (node >= NN) return;
    int lane = g & 63;

    int ro = 0;
    if (lane < 7) ro = rs[node * NBKT + lane];
    int b0 = __builtin_amdgcn_readlane(ro, 0);
    int b1 = __builtin_amdgcn_readlane(ro, 1);
    int b2 = __builtin_amdgcn_readlane(ro, 2);
    int b3 = __builtin_amdgcn_readlane(ro, 3);
    int b4 = __builtin_amdgcn_readlane(ro, 4);
    int b5 = __builtin_amdgcn_readlane(ro, 5);
    int b6 = __builtin_amdgcn_readlane(ro, 6);

    float nk2 = (T >= 1) ? nu_kt[T * MH + 2] : 0.f;
    float nk3 = (T >= 2) ? nu_kt[T * MH + 3] : 0.f;
    float nk4 = (T >= 3) ? nu_kt[T * MH + 4] : 0.f;

    float s0 = 0.f, s1 = 0.f, s2 = 0.f, sH = 0.f;
    int n_all = b6 - b0;
    if (n_all <= 64) {
        int sv = (lane < n_all) ? src_s[b0 + lane] : 0;
        sum_bucket(xt, lane, sv, 0, b1 - b0, 1.f, s0, false);
        sum_bucket(xt, lane, sv, b1 - b0, b2 - b0, 1.f, s1, false);
        sum_bucket(xt, lane, sv, b2 - b0, b3 - b0, 1.f, s2, false);
        if (T >= 1) sum_bucket(d2, lane, sv, b3 - b0, b4 - b0, nk2, sH, true);
        if (T >= 2) sum_bucket(d3, lane, sv, b4 - b0, b5 - b0, nk3, sH, true);
        if (T >= 3) sum_bucket(d4, lane, sv, b5 - b0, b6 - b0, nk4, sH, true);
    } else {
        sum_bucket_g(xt, lane, src_s, b0, b1, 1.f, s0, false);
        sum_bucket_g(xt, lane, src_s, b1, b2, 1.f, s1, false);
        sum_bucket_g(xt, lane, src_s, b2, b3, 1.f, s2, false);
        if (T >= 1) sum_bucket_g(d2, lane, src_s, b3, b4, nk2, sH, true);
        if (T >= 2) sum_bucket_g(d3, lane, src_s, b4, b5, nk3, sH, true);
        if (T >= 3) sum_bucket_g(d4, lane, src_s, b5, b6, nk4, sH, true);
    }

    float nu0 = nu_edge[0 * TL + T], nu1 = nu_edge[1 * TL + T], nu2 = nu_edge[2 * TL + T];
    a0[g] = nu0 * s0;
    a1[g] = nu1 * s1;
    a2[g] = nu2 * s2;
    if (T >= 1) aH[g] = sH;
}

// ---------------- Matmul: 8 nodes per wave, W row reused 8x ----------------

template <int T>
static __global__ __launch_bounds__(256) void k_mm(
        const float* __restrict__ a0, const float* __restrict__ a1,
        const float* __restrict__ a2, const float* __restrict__ aH,
        const float* __restrict__ W_edge, const float* __restrict__ b_edge,
        const float* __restrict__ nu_edge,
        const float* __restrict__ W_t, const float* __restrict__ b_t,
        const float* __restrict__ nu_kt,
        const float* __restrict__ xin, float* __restrict__ xout) {
    int wid = threadIdx.x >> 6;
    int c = threadIdx.x & 63;
    int node0 = (blockIdx.x * 4 + wid) * 8;
    if (node0 >= NN) return;   // NN % 8 == 0, so active waves always have 8 full nodes

    float nu0 = nu_edge[0 * TL + T], nu1 = nu_edge[1 * TL + T], nu2 = nu_edge[2 * TL + T];
    float bias = nu0 * b_edge[(0 * TL + T) * DIM + c]
               + nu1 * b_edge[(1 * TL + T) * DIM + c]
               + nu2 * b_edge[(2 * TL + T) * DIM + c];
    if (T >= 1) {
        float ns = nu_kt[T * MH + 2];
        if (T >= 2) ns += nu_kt[T * MH + 3];
        if (T >= 3) ns += nu_kt[T * MH + 4];
        bias = fmaf(ns, b_t[T * DIM + c], bias);
    }

    float acc[8];
#pragma unroll
    for (int r = 0; r < 8; ++r) acc[r] = bias;

    const int NM = (T >= 1) ? 4 : 3;
#pragma unroll
    for (int m = 0; m < NM; ++m) {
        const float* W = (m == 3) ? (W_t + (size_t)T * DIM * DIM)
                                  : (W_edge + (size_t)(m * TL + T) * DIM * DIM);
        const float* A = ((m == 0) ? a0 : (m == 1) ? a1 : (m == 2) ? a2 : aH)
                         + (size_t)node0 * DIM;
#pragma unroll 4
        for (int d = 0; d < DIM; ++d) {
            float w = W[d * DIM + c];
#pragma unroll
            for (int r = 0; r < 8; ++r) acc[r] = fmaf(A[r * DIM + d], w, acc[r]);
        }
    }

#pragma unroll
    for (int r = 0; r < 8; ++r) {
        int idx = (node0 + r) * DIM + c;
        float v = acc[r];
        v = v > 0.f ? v : 0.f;
        xout[idx] = xin[idx] + v;
    }
}

// ---------------- Host ----------------

extern "C" void kernel_launch(void* const* d_in, const int* in_sizes, int n_in,
                              void* d_out, int out_size, void* d_ws, size_t ws_size,
                              hipStream_t stream) {
    const float* x       = (const float*)d_in[0];
    const float* W_edge  = (const float*)d_in[1];
    const float* b_edge  = (const float*)d_in[2];
    const float* nu_edge = (const float*)d_in[3];
    const float* W_t     = (const float*)d_in[4];
    const float* b_t     = (const float*)d_in[5];
    const float* nu_kt   = (const float*)d_in[6];
    const int* esrc = (const int*)d_in[7];
    const int* edst = (const int*)d_in[8];
    const int* ehop = (const int*)d_in[9];
    const int* etyp = (const int*)d_in[10];
    float* out = (float*)d_out;

    char* ws = (char*)d_ws;
    size_t off = 0;
    auto alloc = [&](size_t bytes) {
        void* p = ws + off;
        off = (off + bytes + 255) & ~(size_t)255;
        return p;
    };
    int* counts = (int*)alloc((size_t)NB * 4);
    int* rs     = (int*)alloc(((size_t)NB + 1) * 4);
    int* cursor = (int*)alloc((size_t)NB * 4);
    int* bsum   = (int*)alloc(1024 * 4);
    int* bexcl  = (int*)alloc(1024 * 4);
    int* src_s  = (int*)alloc((size_t)2 * NE * 4);   // worst case: every edge in a hop bucket too
    float* h1 = (float*)alloc((size_t)NN * DIM * 4);
    float* h2 = (float*)alloc((size_t)NN * DIM * 4);
    float* h3 = (float*)alloc((size_t)NN * DIM * 4);
    float* a0 = (float*)alloc((size_t)NN * DIM * 4);
    float* a1 = (float*)alloc((size_t)NN * DIM * 4);
    float* a2 = (float*)alloc((size_t)NN * DIM * 4);
    float* aH = (float*)alloc((size_t)NN * DIM * 4);
    (void)ws_size; (void)in_sizes; (void)n_in; (void)out_size;

    // CSR build (graph static across layers)
    hipMemsetAsync(counts, 0, (size_t)NB * 4, stream);
    k_hist6<<<(NE + 255) / 256, 256, 0, stream>>>(edst, etyp, ehop, counts);
    k_scanA<<<SCAN_BLK, 1024, 0, stream>>>(counts, rs, bsum);
    k_scanB<<<1, 512, 0, stream>>>(bsum, bexcl, rs);
    k_scanC<<<SCAN_BLK, 1024, 0, stream>>>(rs, cursor, bexcl);
    k_scatter6<<<(NE + 255) / 256, 256, 0, stream>>>(esrc, edst, etyp, ehop, cursor, src_s);

    const int ga = (NN * DIM + 255) / 256;   // one wave per node
    const int gm = (NN + 31) / 32;           // 8 nodes per wave, 4 waves per block

    // t = 0
    k_agg<0><<<ga, 256, 0, stream>>>(rs, src_s, x, x, x, x, nu_edge, nu_kt, a0, a1, a2, aH);
    k_mm<0><<<gm, 256, 0, stream>>>(a0, a1, a2, aH, W_edge, b_edge, nu_edge, W_t, b_t,
                                    nu_kt, x, h1);
    // t = 1: hop2 -> x
    k_agg<1><<<ga, 256, 0, stream>>>(rs, src_s, h1, x, x, x, nu_edge, nu_kt, a0, a1, a2, aH);
    k_mm<1><<<gm, 256, 0, stream>>>(a0, a1, a2, aH, W_edge, b_edge, nu_edge, W_t, b_t,
                                    nu_kt, h1, h2);
    // t = 2: hop2 -> h1, hop3 -> x
    k_agg<2><<<ga, 256, 0, stream>>>(rs, src_s, h2, h1, x, x, nu_edge, nu_kt, a0, a1, a2, aH);
    k_mm<2><<<gm, 256, 0, stream>>>(a0, a1, a2, aH, W_edge, b_edge, nu_edge, W_t, b_t,
                                    nu_kt, h2, h3);
    // t = 3: hop2 -> h2, hop3 -> h1, hop4 -> x
    k_agg<3><<<ga, 256, 0, stream>>>(rs, src_s, h3, h2, h1, x, nu_edge, nu_kt, a0, a1, a2, aH);
    k_mm<3><<<gm, 256, 0, stream>>>(a0, a1, a2, aH, W_edge, b_edge, nu_edge, W_t, b_t,
                                    nu_kt, h3, out);
}

// Round 3
// 663.450 us; speedup vs baseline: 1.8467x; 1.1504x over previous
//
#include <hip/hip_runtime.h>

#define NN 50000
#define NE 800000
#define DIM 64
#define TL 4
#define ET 3
#define MH 6
#define NBKT 6
#define NB (NN * NBKT)
#define SCAN_BLK ((NB + 1023) / 1024)   // 293

// ---------------- CSR build: 6 buckets per node (T0,T1,T2,H2,H3,H4) ----------------

static __global__ void k_hist6(const int* __restrict__ dst, const int* __restrict__ typ,
                               const int* __restrict__ hop, int* __restrict__ counts) {
    int e = blockIdx.x * blockDim.x + threadIdx.x;
    if (e >= NE) return;
    int d = dst[e];
    atomicAdd(&counts[d * NBKT + typ[e]], 1);
    int h = hop[e];
    if (h >= 2 && h <= 4) atomicAdd(&counts[d * NBKT + h + 1], 1);  // buckets 3,4,5
}

static __global__ void k_scanA(const int* __restrict__ counts, int* __restrict__ rs,
                               int* __restrict__ bsum) {
    __shared__ int sm[1024];
    int idx = blockIdx.x * 1024 + threadIdx.x;
    int v = (idx < NB) ? counts[idx] : 0;
    sm[threadIdx.x] = v;
    __syncthreads();
    for (int off = 1; off < 1024; off <<= 1) {
        int t = (threadIdx.x >= off) ? sm[threadIdx.x - off] : 0;
        __syncthreads();
        sm[threadIdx.x] += t;
        __syncthreads();
    }
    if (idx < NB) rs[idx] = sm[threadIdx.x] - v;   // exclusive within block
    if (threadIdx.x == 1023) bsum[blockIdx.x] = sm[1023];
}

static __global__ void k_scanB(const int* __restrict__ bsum, int* __restrict__ bexcl,
                               int* __restrict__ rs) {
    __shared__ int sm[512];
    int tid = threadIdx.x;
    int v = (tid < SCAN_BLK) ? bsum[tid] : 0;
    sm[tid] = v;
    __syncthreads();
    for (int off = 1; off < 512; off <<= 1) {
        int t = (tid >= off) ? sm[tid - off] : 0;
        __syncthreads();
        sm[tid] += t;
        __syncthreads();
    }
    if (tid < SCAN_BLK) bexcl[tid] = sm[tid] - v;
    if (tid == 511) rs[NB] = sm[511];              // grand total
}

static __global__ void k_scanC(int* __restrict__ rs, int* __restrict__ cursor,
                               const int* __restrict__ bexcl) {
    int idx = blockIdx.x * 1024 + threadIdx.x;
    if (idx >= NB) return;
    int r = rs[idx] + bexcl[blockIdx.x];
    rs[idx] = r;
    cursor[idx] = r;
}

static __global__ void k_scatter6(const int* __restrict__ src, const int* __restrict__ dst,
                                  const int* __restrict__ typ, const int* __restrict__ hop,
                                  int* __restrict__ cursor, int* __restrict__ src_s) {
    int e = blockIdx.x * blockDim.x + threadIdx.x;
    if (e >= NE) return;
    int d = dst[e], s = src[e];
    int slot = atomicAdd(&cursor[d * NBKT + typ[e]], 1);
    src_s[slot] = s;
    int h = hop[e];
    if (h >= 2 && h <= 4) {
        slot = atomicAdd(&cursor[d * NBKT + h + 1], 1);
        src_s[slot] = s;
    }
}

// ---------------- Aggregation: one wave per node, merged bucket loops for ILP ----------------

template <int T>
static __global__ __launch_bounds__(256) void k_agg(
        const int* __restrict__ rs, const int* __restrict__ src_s,
        const float* __restrict__ xt, const float* __restrict__ d2,
        const float* __restrict__ d3, const float* __restrict__ d4,
        const float* __restrict__ nu_edge, const float* __restrict__ nu_kt,
        float* __restrict__ a0, float* __restrict__ a1,
        float* __restrict__ a2, float* __restrict__ aH) {
    int g = blockIdx.x * blockDim.x + threadIdx.x;
    int node = g >> 6;
    if (node >= NN) return;
    int lane = g & 63;

    int ro = 0;
    if (lane < 7) ro = rs[node * NBKT + lane];
    const int b0 = __builtin_amdgcn_readlane(ro, 0);
    const int b1 = __builtin_amdgcn_readlane(ro, 1);
    const int b2 = __builtin_amdgcn_readlane(ro, 2);
    const int b3 = __builtin_amdgcn_readlane(ro, 3);
    const int b4 = __builtin_amdgcn_readlane(ro, 4);
    const int b5 = __builtin_amdgcn_readlane(ro, 5);
    const int b6 = __builtin_amdgcn_readlane(ro, 6);

    float s0 = 0.f, s1 = 0.f, s2 = 0.f, sH = 0.f;

    // ---- type section [b0, b3): one merged loop, 3 accs, uniform 0/1 weights ----
    {
        const int nt = b3 - b0;
        const int t1 = b1 - b0, t2 = b2 - b0;
        if (nt <= 64) {
            int sv = (lane < nt) ? src_s[b0 + lane] : 0;
#pragma unroll 4
            for (int i = 0; i < nt; ++i) {
                int sa = __builtin_amdgcn_readlane(sv, i);
                float v = xt[(size_t)sa * DIM + lane];
                float f0 = (i < t1) ? 1.f : 0.f;
                float f1 = (i >= t1 && i < t2) ? 1.f : 0.f;
                float f2 = (i >= t2) ? 1.f : 0.f;
                s0 = fmaf(f0, v, s0);
                s1 = fmaf(f1, v, s1);
                s2 = fmaf(f2, v, s2);
            }
        } else {
#pragma unroll 4
            for (int i = 0; i < nt; ++i) {
                int sa = src_s[b0 + i];
                float v = xt[(size_t)sa * DIM + lane];
                float f0 = (i < t1) ? 1.f : 0.f;
                float f1 = (i >= t1 && i < t2) ? 1.f : 0.f;
                float f2 = (i >= t2) ? 1.f : 0.f;
                s0 = fmaf(f0, v, s0);
                s1 = fmaf(f1, v, s1);
                s2 = fmaf(f2, v, s2);
            }
        }
    }

    // ---- hop section [b3, hend): one merged loop, scale+pointer selected per entry ----
    if (T >= 1) {
        const int hend = (T == 1) ? b4 : (T == 2) ? b5 : b6;
        const int nh = hend - b3;
        const int h1 = b4 - b3, h2 = b5 - b3;
        const float nk2 = nu_kt[T * MH + 2];
        const float nk3 = nu_kt[T * MH + 3];
        const float nk4 = nu_kt[T * MH + 4];
        if (nh <= 64) {
            int sv = (lane < nh) ? src_s[b3 + lane] : 0;
#pragma unroll 4
            for (int i = 0; i < nh; ++i) {
                int sa = __builtin_amdgcn_readlane(sv, i);
                const float* hd = (T == 1) ? d2
                                 : (i < h1) ? d2
                                 : (T == 2) ? d3
                                 : (i < h2) ? d3 : d4;
                float sc = (T == 1) ? nk2
                          : (i < h1) ? nk2
                          : (T == 2) ? nk3
                          : (i < h2) ? nk3 : nk4;
                float v = hd[(size_t)sa * DIM + lane];
                sH = fmaf(sc, v, sH);
            }
        } else {
#pragma unroll 4
            for (int i = 0; i < nh; ++i) {
                int sa = src_s[b3 + i];
                const float* hd = (T == 1) ? d2
                                 : (i < h1) ? d2
                                 : (T == 2) ? d3
                                 : (i < h2) ? d3 : d4;
                float sc = (T == 1) ? nk2
                          : (i < h1) ? nk2
                          : (T == 2) ? nk3
                          : (i < h2) ? nk3 : nk4;
                float v = hd[(size_t)sa * DIM + lane];
                sH = fmaf(sc, v, sH);
            }
        }
    }

    float nu0 = nu_edge[0 * TL + T], nu1 = nu_edge[1 * TL + T], nu2 = nu_edge[2 * TL + T];
    a0[g] = nu0 * s0;
    a1[g] = nu1 * s1;
    a2[g] = nu2 * s2;
    if (T >= 1) aH[g] = sH;
}

// ---------------- Matmul: 8 nodes/wave, A reads uniform (scalar-pipe), W coalesced ----------------

template <int T>
static __global__ __launch_bounds__(256) void k_mm(
        const float* __restrict__ a0, const float* __restrict__ a1,
        const float* __restrict__ a2, const float* __restrict__ aH,
        const float* __restrict__ W_edge, const float* __restrict__ b_edge,
        const float* __restrict__ nu_edge,
        const float* __restrict__ W_t, const float* __restrict__ b_t,
        const float* __restrict__ nu_kt,
        const float* __restrict__ xin, float* __restrict__ xout) {
    // readfirstlane makes wid compiler-uniform -> A addresses provably wave-uniform
    const int wid = __builtin_amdgcn_readfirstlane(threadIdx.x >> 6);
    const int c = threadIdx.x & 63;
    const int node0 = blockIdx.x * 32 + wid * 8;
    if (node0 >= NN) return;   // NN % 8 == 0: active waves always own 8 full nodes

    const float nu0 = nu_edge[0 * TL + T], nu1 = nu_edge[1 * TL + T],
                nu2 = nu_edge[2 * TL + T];
    float bias = nu0 * b_edge[(0 * TL + T) * DIM + c]
               + nu1 * b_edge[(1 * TL + T) * DIM + c]
               + nu2 * b_edge[(2 * TL + T) * DIM + c];
    if (T >= 1) {
        float ns = nu_kt[T * MH + 2];
        if (T >= 2) ns += nu_kt[T * MH + 3];
        if (T >= 3) ns += nu_kt[T * MH + 4];
        bias = fmaf(ns, b_t[T * DIM + c], bias);
    }

    float acc[8];
#pragma unroll
    for (int r = 0; r < 8; ++r) acc[r] = bias;

    const float* As[4] = {a0, a1, a2, aH};
    constexpr int NM = (T >= 1) ? 4 : 3;
#pragma unroll
    for (int m = 0; m < NM; ++m) {
        const float* __restrict__ W = (m == 3) ? (W_t + (size_t)T * DIM * DIM)
                                               : (W_edge + (size_t)(m * TL + T) * DIM * DIM);
        const float* __restrict__ A = As[m] + (size_t)node0 * DIM;
        for (int d = 0; d < DIM; d += 4) {
            float w0 = W[(d + 0) * DIM + c];
            float w1 = W[(d + 1) * DIM + c];
            float w2 = W[(d + 2) * DIM + c];
            float w3 = W[(d + 3) * DIM + c];
#pragma unroll
            for (int r = 0; r < 8; ++r) {
                float4 av = *(const float4*)(A + r * DIM + d);   // uniform addr -> s_load
                acc[r] = fmaf(av.x, w0, acc[r]);
                acc[r] = fmaf(av.y, w1, acc[r]);
                acc[r] = fmaf(av.z, w2, acc[r]);
                acc[r] = fmaf(av.w, w3, acc[r]);
            }
        }
    }

#pragma unroll
    for (int r = 0; r < 8; ++r) {
        size_t idx = (size_t)(node0 + r) * DIM + c;
        float v = acc[r] > 0.f ? acc[r] : 0.f;
        xout[idx] = xin[idx] + v;
    }
}

// ---------------- Host ----------------

extern "C" void kernel_launch(void* const* d_in, const int* in_sizes, int n_in,
                              void* d_out, int out_size, void* d_ws, size_t ws_size,
                              hipStream_t stream) {
    const float* x       = (const float*)d_in[0];
    const float* W_edge  = (const float*)d_in[1];
    const float* b_edge  = (const float*)d_in[2];
    const float* nu_edge = (const float*)d_in[3];
    const float* W_t     = (const float*)d_in[4];
    const float* b_t     = (const float*)d_in[5];
    const float* nu_kt   = (const float*)d_in[6];
    const int* esrc = (const int*)d_in[7];
    const int* edst = (const int*)d_in[8];
    const int* ehop = (const int*)d_in[9];
    const int* etyp = (const int*)d_in[10];
    float* out = (float*)d_out;

    char* ws = (char*)d_ws;
    size_t off = 0;
    auto alloc = [&](size_t bytes) {
        void* p = ws + off;
        off = (off + bytes + 255) & ~(size_t)255;
        return p;
    };
    int* counts = (int*)alloc((size_t)NB * 4);
    int* rs     = (int*)alloc(((size_t)NB + 1) * 4);
    int* cursor = (int*)alloc((size_t)NB * 4);
    int* bsum   = (int*)alloc(1024 * 4);
    int* bexcl  = (int*)alloc(1024 * 4);
    int* src_s  = (int*)alloc((size_t)2 * NE * 4);
    float* h1 = (float*)alloc((size_t)NN * DIM * 4);
    float* h2 = (float*)alloc((size_t)NN * DIM * 4);
    float* h3 = (float*)alloc((size_t)NN * DIM * 4);
    float* a0 = (float*)alloc((size_t)NN * DIM * 4);
    float* a1 = (float*)alloc((size_t)NN * DIM * 4);
    float* a2 = (float*)alloc((size_t)NN * DIM * 4);
    float* aH = (float*)alloc((size_t)NN * DIM * 4);
    (void)ws_size; (void)in_sizes; (void)n_in; (void)out_size;

    // CSR build (graph static across layers)
    hipMemsetAsync(counts, 0, (size_t)NB * 4, stream);
    k_hist6<<<(NE + 255) / 256, 256, 0, stream>>>(edst, etyp, ehop, counts);
    k_scanA<<<SCAN_BLK, 1024, 0, stream>>>(counts, rs, bsum);
    k_scanB<<<1, 512, 0, stream>>>(bsum, bexcl, rs);
    k_scanC<<<SCAN_BLK, 1024, 0, stream>>>(rs, cursor, bexcl);
    k_scatter6<<<(NE + 255) / 256, 256, 0, stream>>>(esrc, edst, etyp, ehop, cursor, src_s);

    const int ga = (NN * DIM + 255) / 256;   // one wave per node
    const int gm = (NN + 31) / 32;           // 8 nodes per wave, 4 waves per block

    // t = 0
    k_agg<0><<<ga, 256, 0, stream>>>(rs, src_s, x, x, x, x, nu_edge, nu_kt, a0, a1, a2, aH);
    k_mm<0><<<gm, 256, 0, stream>>>(a0, a1, a2, aH, W_edge, b_edge, nu_edge, W_t, b_t,
                                    nu_kt, x, h1);
    // t = 1: hop2 -> x
    k_agg<1><<<ga, 256, 0, stream>>>(rs, src_s, h1, x, x, x, nu_edge, nu_kt, a0, a1, a2, aH);
    k_mm<1><<<gm, 256, 0, stream>>>(a0, a1, a2, aH, W_edge, b_edge, nu_edge, W_t, b_t,
                                    nu_kt, h1, h2);
    // t = 2: hop2 -> h1, hop3 -> x
    k_agg<2><<<ga, 256, 0, stream>>>(rs, src_s, h2, h1, x, x, nu_edge, nu_kt, a0, a1, a2, aH);
    k_mm<2><<<gm, 256, 0, stream>>>(a0, a1, a2, aH, W_edge, b_edge, nu_edge, W_t, b_t,
                                    nu_kt, h2, h3);
    // t = 3: hop2 -> h2, hop3 -> h1, hop4 -> x
    k_agg<3><<<ga, 256, 0, stream>>>(rs, src_s, h3, h2, h1, x, nu_edge, nu_kt, a0, a1, a2, aH);
    k_mm<3><<<gm, 256, 0, stream>>>(a0, a1, a2, aH, W_edge, b_edge, nu_edge, W_t, b_t,
                                    nu_kt, h3, out);
}